// Round 4
// baseline (784.380 us; speedup 1.0000x reference)
//
#include <hip/hip_runtime.h>
#include <cstdint>
#include <cstddef>

// LSTM B=256,S=512,C=64,H=128, 2 layers, gates i,f,g,o (torch order).
// Round 4: hoist the input GEMM out of the recurrence.
// 128 blocks x 512 threads: blocks 0-63 layer 0 (4 batch rows each),
// blocks 64-127 layer 1 (4 rows, consumes y1 chunks via tokened flags).
// Per 4-step sub-chunk, each block bulk-computes xg = x*Wih^T + bias into a
// 32KB f32 LDS buffer with FULL 16-row MFMA tiles (rows = 4 steps x 4 batch),
// then runs 4 lean recurrence steps: 16 whh-MFMA + 1-row elementwise.
// c-state fp32 in registers; h double-buffered in LDS (1 barrier/step).

#define S_LEN 512
#define B_SZ  256
#define C_IN  64
#define HDIM  128
#define CH    16
#define NPAIR 64            // blocks per layer, 4 rows each

using short8  = __attribute__((ext_vector_type(8))) short;   // 8 bf16
using float4v = __attribute__((ext_vector_type(4))) float;

__device__ __forceinline__ unsigned short f2b(float f) {
    union { float f; unsigned int u; } v; v.f = f;
    unsigned int u = v.u;
    return (unsigned short)((u + 0x7FFFu + ((u >> 16) & 1u)) >> 16);
}
__device__ __forceinline__ float sig_(float x) {
    return __builtin_amdgcn_rcpf(1.0f + __builtin_amdgcn_exp2f(x * -1.442695041f));
}
__device__ __forceinline__ float tanh_(float x) {
    return 1.0f - 2.0f * __builtin_amdgcn_rcpf(1.0f + __builtin_amdgcn_exp2f(x * 2.885390082f));
}

__global__ void prep_kernel(const float* __restrict__ x,
                            const float* __restrict__ wih0, const float* __restrict__ whh0,
                            const float* __restrict__ bih0, const float* __restrict__ bhh0,
                            const float* __restrict__ wih1, const float* __restrict__ whh1,
                            const float* __restrict__ bih1, const float* __restrict__ bhh1,
                            unsigned short* __restrict__ whh0_b, unsigned short* __restrict__ wih0_b,
                            unsigned short* __restrict__ whh1_b, unsigned short* __restrict__ wih1_b,
                            float* __restrict__ bias0, float* __restrict__ bias1,
                            unsigned short* __restrict__ xb) {
    int i = blockIdx.x * blockDim.x + threadIdx.x;
    if (i < B_SZ * S_LEN * C_IN) xb[i] = f2b(x[i]);
    if (i < 4 * HDIM * HDIM) {
        whh0_b[i] = f2b(whh0[i]);
        whh1_b[i] = f2b(whh1[i]);
        wih1_b[i] = f2b(wih1[i]);
    }
    if (i < 4 * HDIM * C_IN) wih0_b[i] = f2b(wih0[i]);
    if (i < 4 * HDIM) {
        bias0[i] = bih0[i] + bhh0[i];
        bias1[i] = bih1[i] + bhh1[i];
    }
}

// MFMA 16x16x32 bf16 frags (verified rounds 1-3):
//   A[m=lane&15][k=(lane>>4)*8+jj], B == W[n=lane&15][k] 16B row chunk,
//   D[m=4*(lane>>4)+reg][n=lane&15]
// Block owns batch rows boff..boff+3. Tile rows for the recurrence h-matmul:
// only m%4==0 valid (batch row m/4); rows m%4!=0 of hbuf stay zero.
// Hoisted GEMM uses FULL tiles: row m of sub-chunk tile = (step m>>2, batch m&3).
template<int KIN, bool IS_L0>
__device__ __forceinline__ void lstm_layer(
    unsigned short* hbuf,                         // 2 x 2048 shorts (16x128 each)
    float* xgf,                                   // 4 steps x 8 w x 64 lanes x 4 f32 (32KB)
    const unsigned short* __restrict__ in_seq,    // L0: xb (B,S,C); L1: y1 (S,B,H)
    const unsigned short* __restrict__ wih_b,     // (512,KIN) bf16
    const unsigned short* __restrict__ whh_b,     // (512,128) bf16
    const float* __restrict__ bias,               // (512,) f32
    unsigned short* __restrict__ y1,              // L0 out (S,B,H) bf16
    float* __restrict__ final_out,                // L1 out (B,H) f32
    int* __restrict__ flags, int blk) {
    constexpr int KK = KIN / 32;
    const int tid = threadIdx.x;
    const int w = tid >> 6, L = tid & 63, q = L >> 4, r = L & 15;
    const int boff = blk * 4, j0 = w * 16, j = j0 + r;

    // register-resident weights
    short8 whh[4][4], wih[4][KK];
    float bias_s[4];
#pragma unroll
    for (int g = 0; g < 4; ++g) {
        const int nrow = g * HDIM + j;
#pragma unroll
        for (int kk = 0; kk < 4; ++kk)
            whh[g][kk] = *(const short8*)(whh_b + (size_t)nrow * HDIM + kk * 32 + q * 8);
#pragma unroll
        for (int kk = 0; kk < KK; ++kk)
            wih[g][kk] = *(const short8*)(wih_b + (size_t)nrow * KIN + kk * 32 + q * 8);
        bias_s[g] = bias[g * HDIM + j];
    }

    for (int idx = tid; idx < 4096; idx += 512) hbuf[idx] = 0;  // both h buffers
    float cf = 0.f;

    // A-frags for the hoisted GEMM: lane r = tile row (step r>>2, batch r&3)
    short8 af[KK];
    auto loadA = [&](int ch, int sub) {
        const int t = ch * CH + sub * 4 + (r >> 2);
        const int b = boff + (r & 3);
        const unsigned short* base;
        if constexpr (IS_L0) base = in_seq + ((size_t)b * S_LEN + t) * C_IN;
        else                 base = in_seq + ((size_t)t * B_SZ + b) * HDIM;
#pragma unroll
        for (int kk = 0; kk < KK; ++kk)
            af[kk] = *(const short8*)(base + kk * 32 + q * 8);
    };

    if constexpr (IS_L0) loadA(0, 0);

    for (int ch = 0; ch < 32; ++ch) {
        if constexpr (!IS_L0) {
            if (tid == 0)
                while (__hip_atomic_load(flags + blk * 32 + ch, __ATOMIC_ACQUIRE,
                                         __HIP_MEMORY_SCOPE_AGENT) != ch + 1)
                    __builtin_amdgcn_s_sleep(2);
            __syncthreads();        // gate: y1 chunk visible to all threads
            loadA(ch, 0);
        }
#pragma unroll 1
        for (int sub = 0; sub < 4; ++sub) {
            // ---- hoisted input GEMM for the next 4 steps ----
            // D element (g, reg rr) of lane (q,r): row m=4q+rr -> (step q, batch rr),
            // col g*128+j. Consumer (step q, lane q_c=rr, r_c=r, wave w): scatter:
#pragma unroll
            for (int g = 0; g < 4; ++g) {
                float4v a = {0.f, 0.f, 0.f, 0.f};
#pragma unroll
                for (int kk = 0; kk < KK; ++kk)
                    a = __builtin_amdgcn_mfma_f32_16x16x32_bf16(af[kk], wih[g][kk], a, 0, 0, 0);
#pragma unroll
                for (int rr = 0; rr < 4; ++rr)
                    xgf[((q * 8 + w) * 64 + rr * 16 + r) * 4 + g] = a[rr] + bias_s[g];
            }
            // prefetch next sub-chunk's A-frags (next chunk needs L1 flag: skip)
            if (sub < 3) loadA(ch, sub + 1);
            else if (IS_L0 && ch < 31) loadA(ch + 1, 0);
            __syncthreads();   // xg ready (also: prior steps done reading old xg)

            // ---- 4 lean recurrence steps ----
#pragma unroll
            for (int sl = 0; sl < 4; ++sl) {
                const int s = sub * 4 + sl;
                const int t = ch * CH + s;
                unsigned short* cur = hbuf + (s & 1) * 2048;
                unsigned short* nxt = hbuf + ((s & 1) ^ 1) * 2048;
                short8 hfrag[4];
#pragma unroll
                for (int kk = 0; kk < 4; ++kk)
                    hfrag[kk] = *(const short8*)(cur + ((kk * 4 + q) * 16 + r) * 8);
                const float4v xv = ((const float4v*)xgf)[(sl * 8 + w) * 64 + L];
                float4v a0 = {xv[0], 0.f, 0.f, 0.f};
                float4v a1 = {xv[1], 0.f, 0.f, 0.f};
                float4v a2 = {xv[2], 0.f, 0.f, 0.f};
                float4v a3 = {xv[3], 0.f, 0.f, 0.f};
#pragma unroll
                for (int kk = 0; kk < 4; ++kk) {
                    a0 = __builtin_amdgcn_mfma_f32_16x16x32_bf16(hfrag[kk], whh[0][kk], a0, 0, 0, 0);
                    a1 = __builtin_amdgcn_mfma_f32_16x16x32_bf16(hfrag[kk], whh[1][kk], a1, 0, 0, 0);
                    a2 = __builtin_amdgcn_mfma_f32_16x16x32_bf16(hfrag[kk], whh[2][kk], a2, 0, 0, 0);
                    a3 = __builtin_amdgcn_mfma_f32_16x16x32_bf16(hfrag[kk], whh[3][kk], a3, 0, 0, 0);
                }
                // elementwise, 1 valid row per lane (tile row 4q = batch row q)
                const float iv = sig_(a0[0]);
                const float fv = sig_(a1[0]);
                const float gv = tanh_(a2[0]);
                const float ov = sig_(a3[0]);
                cf = fv * cf + iv * gv;
                const float hv = ov * tanh_(cf);
                nxt[(j >> 3) * 128 + 32 * q + (j & 7)] = f2b(hv);
                if constexpr (!IS_L0) {
                    if (t == S_LEN - 1)
                        final_out[(size_t)(boff + q) * HDIM + j] = hv;
                }
                __syncthreads();   // h_t visible (double buffer: 1 barrier/step)
                if constexpr (IS_L0) {
                    // coalesced h_t -> y1[t]: 64 lanes x 16B (row L>>4, col chunk L&15)
                    if (tid < 64)
                        *(short8*)(y1 + ((size_t)t * B_SZ + boff + (L >> 4)) * HDIM + (L & 15) * 8)
                            = *(const short8*)(nxt + (L & 15) * 128 + (L >> 4) * 32);
                }
            }
        }
        if constexpr (IS_L0) {
            __threadfence();       // y1 chunk stores visible device-wide
            __syncthreads();
            if (tid == 0)
                __hip_atomic_store(flags + blk * 32 + ch, ch + 1, __ATOMIC_RELEASE,
                                   __HIP_MEMORY_SCOPE_AGENT);
        }
    }
}

__global__ __launch_bounds__(512, 2)
void lstm_pipe(const unsigned short* __restrict__ xb,
               const unsigned short* __restrict__ wih0_b, const unsigned short* __restrict__ whh0_b,
               const float* __restrict__ bias0,
               const unsigned short* __restrict__ wih1_b, const unsigned short* __restrict__ whh1_b,
               const float* __restrict__ bias1,
               unsigned short* __restrict__ y1, float* __restrict__ out,
               int* __restrict__ flags) {
    __shared__ __align__(16) unsigned short hbuf[2 * 2048];   //  8 KB
    __shared__ __align__(16) float xgf[4 * 8 * 64 * 4];       // 32 KB
    if (blockIdx.x < NPAIR)
        lstm_layer<C_IN, true>(hbuf, xgf, xb, wih0_b, whh0_b, bias0, y1, nullptr,
                               flags, blockIdx.x);
    else
        lstm_layer<HDIM, false>(hbuf, xgf, y1, wih1_b, whh1_b, bias1, nullptr, out,
                                flags, blockIdx.x - NPAIR);
}

// ---- workspace layout (bytes) ----
//       0 : whh0_b 131072
//  131072 : wih0_b  65536
//  196608 : whh1_b 131072
//  327680 : wih1_b 131072
//  458752 : bias0    2048
//  460800 : bias1    2048
//  462848 : flags    8192  (64 blocks x 32 chunks, memset 0 each launch)
//  524288 : xb   16777216
// 17301504: y1   33554432

extern "C" void kernel_launch(void* const* d_in, const int* in_sizes, int n_in,
                              void* d_out, int out_size, void* d_ws, size_t ws_size,
                              hipStream_t stream) {
    const float* x    = (const float*)d_in[0];
    const float* wih0 = (const float*)d_in[1];
    const float* whh0 = (const float*)d_in[2];
    const float* bih0 = (const float*)d_in[3];
    const float* bhh0 = (const float*)d_in[4];
    const float* wih1 = (const float*)d_in[5];
    const float* whh1 = (const float*)d_in[6];
    const float* bih1 = (const float*)d_in[7];
    const float* bhh1 = (const float*)d_in[8];

    char* ws = (char*)d_ws;
    unsigned short* whh0_b = (unsigned short*)(ws + 0);
    unsigned short* wih0_b = (unsigned short*)(ws + 131072);
    unsigned short* whh1_b = (unsigned short*)(ws + 196608);
    unsigned short* wih1_b = (unsigned short*)(ws + 327680);
    float*          bias0  = (float*)(ws + 458752);
    float*          bias1  = (float*)(ws + 460800);
    int*            flags  = (int*)(ws + 462848);
    unsigned short* xb     = (unsigned short*)(ws + 524288);
    unsigned short* y1     = (unsigned short*)(ws + 17301504);

    hipMemsetAsync(flags, 0, 8192, stream);

    prep_kernel<<<(B_SZ * S_LEN * C_IN + 255) / 256, 256, 0, stream>>>(
        x, wih0, whh0, bih0, bhh0, wih1, whh1, bih1, bhh1,
        whh0_b, wih0_b, whh1_b, wih1_b, bias0, bias1, xb);

    lstm_pipe<<<dim3(2 * NPAIR), dim3(512), 0, stream>>>(
        xb, wih0_b, whh0_b, bias0, wih1_b, whh1_b, bias1, y1, (float*)d_out, flags);
}